// Round 1
// baseline (193.474 us; speedup 1.0000x reference)
//
#include <hip/hip_runtime.h>
#include <hip/hip_bf16.h>

// NPZD plankton ODE: B*WK independent trajectories, 56 Euler steps,
// forcing gathered from global_f/global_m at stride-3 within week blocks.
// Memory-bound: ~160 MB traffic -> ~25 us floor at 6.3 TB/s.

#define NPZD_B 2048
#define NPZD_WK 52
#define NPZD_HRS 8760
#define NPZD_NSTEPS 56
#define NPZD_CHUNK 8
#define NPZD_NCHUNK 7

__global__ __launch_bounds__(256) void npzd_kernel(
    const float* __restrict__ X_in,     // (B, WK, 5, 1)
    const float* __restrict__ gf,       // (B, HRS)
    const float* __restrict__ gm,       // (B, HRS)
    const float* __restrict__ params,   // (B, 10)
    const float* __restrict__ dt_ptr,   // scalar
    float* __restrict__ out)            // (B, WK, 4, 8)
{
    const int t = blockIdx.x * blockDim.x + threadIdx.x;
    if (t >= NPZD_B * NPZD_WK) return;
    const int b = t / NPZD_WK;
    const int w = t - b * NPZD_WK;

    const float dt = dt_ptr[0];   // 0.125

    // initial state
    const float* xb = X_in + (size_t)t * 5;
    float N = xb[1], P = xb[2], Z = xb[3], D = xb[4];

    // time base: reference uses batch 0's time row
    const float t0w = X_in[(size_t)w * 5];
    const int idx0 = (int)rintf(t0w * 24.0f);      // == w*168
    const float* __restrict__ frow = gf + (size_t)b * NPZD_HRS + idx0;
    const float* __restrict__ mrow = gm + (size_t)b * NPZD_HRS + idx0;

    // fold fixed pv[] into per-batch params
    const float* pp = params + (size_t)b * 10;
    const float chi   = pp[0] * 1.0f;
    const float rho2  = pp[1] * 2.0f;
    const float gam1  = pp[2] * 0.1f;
    const float lam05 = pp[3] * 0.05f;
    const float eps1  = pp[4] * 0.1f;
    const float alp3  = pp[5] * 0.3f;
    const float bet6  = pp[6] * 0.6f;
    const float eta15 = pp[7] * 0.15f;
    const float phi4  = pp[8] * 0.4f;
    const float zet1  = pp[9] * 0.1f;
    const float rem   = 1.0f - alp3 - bet6;

    float oN[NPZD_NCHUNK + 1], oP[NPZD_NCHUNK + 1], oZ[NPZD_NCHUNK + 1], oD[NPZD_NCHUNK + 1];
    oN[0] = N; oP[0] = P; oZ[0] = Z; oD[0] = D;

    // prefetch chunk 0 (8 f + 8 m, stride-3 gather; dt*24 == 3)
    float fcur[NPZD_CHUNK], mcur[NPZD_CHUNK];
    #pragma unroll
    for (int i = 0; i < NPZD_CHUNK; ++i) {
        fcur[i] = frow[3 * i];
        mcur[i] = mrow[3 * i];
    }

    #pragma unroll
    for (int c = 0; c < NPZD_NCHUNK; ++c) {
        // prefetch next chunk while computing this one.
        // Note: even for c==6 the addresses stay in-bounds (max offset
        // idx0+189 <= 8568+189 = 8757 < 8760), so load unconditionally.
        float fnxt[NPZD_CHUNK], mnxt[NPZD_CHUNK];
        {
            const float* fn = frow + (c + 1) * 24;
            const float* mn = mrow + (c + 1) * 24;
            #pragma unroll
            for (int i = 0; i < NPZD_CHUNK; ++i) {
                fnxt[i] = fn[3 * i];
                mnxt[i] = mn[3 * i];
            }
        }
        #pragma unroll
        for (int i = 0; i < NPZD_CHUNK; ++i) {
            const float ft = fcur[i], mt = mcur[i];
            const float Pc = fmaxf(0.01f, P);
            const float Zc = fmaxf(0.01f, Z);
            const float gN = N / (chi + N);
            const float zg = rho2 * (1.0f - __expf(-lam05 * Pc)) * Zc;
            const float up = gN * ft * Pc;
            const float Nn = N + dt * (-up + alp3 * zg + eps1 * P + gam1 * Z + phi4 * D + mt * (8.0f - N));
            const float Pn = P + dt * (up - zg - eps1 * P - eta15 * P - mt * P);
            const float Zn = Z + dt * (bet6 * zg - gam1 * Z - mt * Z);
            const float Dn = D + dt * (eta15 * P + rem * zg - phi4 * D - zet1 * D - mt * D);
            N = Nn; P = Pn; Z = Zn; D = Dn;
        }
        oN[c + 1] = N; oP[c + 1] = P; oZ[c + 1] = Z; oD[c + 1] = D;
        #pragma unroll
        for (int i = 0; i < NPZD_CHUNK; ++i) {
            fcur[i] = fnxt[i];
            mcur[i] = mnxt[i];
        }
    }

    // out layout: (b, w, state, 8) -> 32 contiguous floats per trajectory.
    float4* o4 = (float4*)(out + (size_t)t * 32);
    o4[0] = make_float4(oN[0], oN[1], oN[2], oN[3]);
    o4[1] = make_float4(oN[4], oN[5], oN[6], oN[7]);
    o4[2] = make_float4(oP[0], oP[1], oP[2], oP[3]);
    o4[3] = make_float4(oP[4], oP[5], oP[6], oP[7]);
    o4[4] = make_float4(oZ[0], oZ[1], oZ[2], oZ[3]);
    o4[5] = make_float4(oZ[4], oZ[5], oZ[6], oZ[7]);
    o4[6] = make_float4(oD[0], oD[1], oD[2], oD[3]);
    o4[7] = make_float4(oD[4], oD[5], oD[6], oD[7]);
}

extern "C" void kernel_launch(void* const* d_in, const int* in_sizes, int n_in,
                              void* d_out, int out_size, void* d_ws, size_t ws_size,
                              hipStream_t stream) {
    const float* X_in   = (const float*)d_in[0];
    const float* gf     = (const float*)d_in[1];
    const float* gm     = (const float*)d_in[2];
    const float* params = (const float*)d_in[3];
    const float* dt_ptr = (const float*)d_in[4];
    float* out = (float*)d_out;

    const int n = NPZD_B * NPZD_WK;          // 106496 trajectories
    const int block = 256;
    const int grid = (n + block - 1) / block; // 416 blocks
    npzd_kernel<<<grid, block, 0, stream>>>(X_in, gf, gm, params, dt_ptr, out);
}

// Round 2
// 187.347 us; speedup vs baseline: 1.0327x; 1.0327x over previous
//
#include <hip/hip_runtime.h>
#include <hip/hip_bf16.h>

// NPZD plankton ODE: B*WK = 106496 independent trajectories, 56 Euler steps.
// Memory-bound: ~144 MB forcing traffic -> ~23 us floor at 6.3 TB/s.
//
// R2 design: latency-bound fix. Load ALL 112 forcing values (56 f + 56 m,
// stride-3 gather) into registers BEFORE any compute, so the wave has ~60+
// loads in flight (vmcnt-limited) instead of the serialized load-wait chain
// the compiler produced from the R1 double-buffer (VGPR_Count=36 proved it).
// block=64 -> 1664 blocks -> 6.5 blocks/CU, <=8% tail imbalance.

#define NPZD_B 2048
#define NPZD_WK 52
#define NPZD_HRS 8760
#define NPZD_NSTEPS 56

__global__ __launch_bounds__(64) void npzd_kernel(
    const float* __restrict__ X_in,     // (B, WK, 5, 1)
    const float* __restrict__ gf,       // (B, HRS)
    const float* __restrict__ gm,       // (B, HRS)
    const float* __restrict__ params,   // (B, 10)
    const float* __restrict__ dt_ptr,   // scalar
    float* __restrict__ out)            // (B, WK, 4, 8)
{
    const int t = blockIdx.x * blockDim.x + threadIdx.x;
    if (t >= NPZD_B * NPZD_WK) return;
    const int b = t / NPZD_WK;
    const int w = t - b * NPZD_WK;

    // time base: reference uses batch 0's time row; t0[w] = 7w, *24 = 168w,
    // dt*24 = 3 exactly -> idx = w*168 + 3*s (exact in fp32, verified R1).
    const float t0w = X_in[(size_t)w * 5];
    const int idx0 = (int)rintf(t0w * 24.0f);
    const float* __restrict__ frow = gf + (size_t)b * NPZD_HRS + idx0;
    const float* __restrict__ mrow = gm + (size_t)b * NPZD_HRS + idx0;

    // ---- Phase 1: issue all forcing gathers up front (max MLP) ----
    float fv[NPZD_NSTEPS], mv[NPZD_NSTEPS];
    #pragma unroll
    for (int i = 0; i < NPZD_NSTEPS; ++i) fv[i] = frow[3 * i];
    #pragma unroll
    for (int i = 0; i < NPZD_NSTEPS; ++i) mv[i] = mrow[3 * i];

    const float dt = dt_ptr[0];   // 0.125

    // initial state
    const float* xb = X_in + (size_t)t * 5;
    float N = xb[1], P = xb[2], Z = xb[3], D = xb[4];

    // fold fixed pv[] into per-batch params
    const float* pp = params + (size_t)b * 10;
    const float chi   = pp[0];
    const float rho2  = pp[1] * 2.0f;
    const float gam1  = pp[2] * 0.1f;
    const float lam05 = pp[3] * 0.05f;
    const float eps1  = pp[4] * 0.1f;
    const float alp3  = pp[5] * 0.3f;
    const float bet6  = pp[6] * 0.6f;
    const float eta15 = pp[7] * 0.15f;
    const float phi4  = pp[8] * 0.4f;
    const float zet1  = pp[9] * 0.1f;
    const float rem   = 1.0f - alp3 - bet6;

    // ---- Phase 2: 56 Euler steps from registers ----
    float oN[8], oP[8], oZ[8], oD[8];
    oN[0] = N; oP[0] = P; oZ[0] = Z; oD[0] = D;

    #pragma unroll
    for (int s = 0; s < NPZD_NSTEPS; ++s) {
        const float ft = fv[s], mt = mv[s];
        const float Pc = fmaxf(0.01f, P);
        const float Zc = fmaxf(0.01f, Z);
        const float gN = N / (chi + N);
        const float zg = rho2 * (1.0f - __expf(-lam05 * Pc)) * Zc;
        const float up = gN * ft * Pc;
        const float Nn = N + dt * (-up + alp3 * zg + eps1 * P + gam1 * Z + phi4 * D + mt * (8.0f - N));
        const float Pn = P + dt * (up - zg - eps1 * P - eta15 * P - mt * P);
        const float Zn = Z + dt * (bet6 * zg - gam1 * Z - mt * Z);
        const float Dn = D + dt * (eta15 * P + rem * zg - phi4 * D - zet1 * D - mt * D);
        N = Nn; P = Pn; Z = Zn; D = Dn;
        if ((s & 7) == 7) {
            const int c = (s >> 3) + 1;
            oN[c] = N; oP[c] = P; oZ[c] = Z; oD[c] = D;
        }
    }

    // ---- Phase 3: coalesced-ish output, 8 x float4 per trajectory ----
    float4* o4 = (float4*)(out + (size_t)t * 32);
    o4[0] = make_float4(oN[0], oN[1], oN[2], oN[3]);
    o4[1] = make_float4(oN[4], oN[5], oN[6], oN[7]);
    o4[2] = make_float4(oP[0], oP[1], oP[2], oP[3]);
    o4[3] = make_float4(oP[4], oP[5], oP[6], oP[7]);
    o4[4] = make_float4(oZ[0], oZ[1], oZ[2], oZ[3]);
    o4[5] = make_float4(oZ[4], oZ[5], oZ[6], oZ[7]);
    o4[6] = make_float4(oD[0], oD[1], oD[2], oD[3]);
    o4[7] = make_float4(oD[4], oD[5], oD[6], oD[7]);
}

extern "C" void kernel_launch(void* const* d_in, const int* in_sizes, int n_in,
                              void* d_out, int out_size, void* d_ws, size_t ws_size,
                              hipStream_t stream) {
    const float* X_in   = (const float*)d_in[0];
    const float* gf     = (const float*)d_in[1];
    const float* gm     = (const float*)d_in[2];
    const float* params = (const float*)d_in[3];
    const float* dt_ptr = (const float*)d_in[4];
    float* out = (float*)d_out;

    const int n = NPZD_B * NPZD_WK;            // 106496 trajectories
    const int block = 64;                      // 1 wave/block -> 1664 blocks
    const int grid = (n + block - 1) / block;  // 6.5 blocks/CU, small tail
    npzd_kernel<<<grid, block, 0, stream>>>(X_in, gf, gm, params, dt_ptr, out);
}

// Round 3
// 182.200 us; speedup vs baseline: 1.0619x; 1.0282x over previous
//
#include <hip/hip_runtime.h>
#include <hip/hip_bf16.h>

// NPZD plankton ODE: B*WK = 106496 independent trajectories, 56 Euler steps.
// Memory-bound: ~145 MB forcing reads + 13.6 MB writes -> ~25 us floor.
//
// R3 design: one block per batch b. Phase 1: 256 threads cooperatively
// gather the 2912 f + 2912 m forcing values for this batch into LDS
// (independent loads, can't be sunk past the barrier -> real MLP; R1/R2
// proved the compiler serializes per-thread register prefetch, VGPR=36).
// Phase 2: lanes 0..51 integrate one trajectory each from LDS.
// LDS 23.9 KB/block -> 6 blocks/CU -> 24 waves/CU of TLP on top.

#define NPZD_B 2048
#define NPZD_WK 52
#define NPZD_HRS 8760
#define NPZD_NSTEPS 56
#define NPZD_PAD 57                       // 25w+s mod 32 -> <=2-way banks (free)
#define NPZD_NK (NPZD_WK * NPZD_NSTEPS)   // 2912 gathers per array

__global__ __launch_bounds__(256) void npzd_kernel(
    const float* __restrict__ X_in,     // (B, WK, 5, 1)
    const float* __restrict__ gf,       // (B, HRS)
    const float* __restrict__ gm,       // (B, HRS)
    const float* __restrict__ params,   // (B, 10)
    const float* __restrict__ dt_ptr,   // scalar
    float* __restrict__ out)            // (B, WK, 4, 8)
{
    __shared__ float lds_f[NPZD_WK * NPZD_PAD];
    __shared__ float lds_m[NPZD_WK * NPZD_PAD];
    __shared__ int   lds_idx[NPZD_WK];

    const int b   = blockIdx.x;
    const int tid = threadIdx.x;

    // Phase 0: per-week gather base from the reference's time row
    // (X_in[0, w, 0, 0]; idx = rint(t0*24), step dt*24 == 3 exact).
    if (tid < NPZD_WK) {
        const float t0w = X_in[(size_t)tid * 5];
        lds_idx[tid] = (int)rintf(t0w * 24.0f);
    }
    __syncthreads();

    // Phase 1: cooperative gather of all forcing values into LDS.
    const float* __restrict__ frow = gf + (size_t)b * NPZD_HRS;
    const float* __restrict__ mrow = gm + (size_t)b * NPZD_HRS;
    #pragma unroll
    for (int j = 0; j < (NPZD_NK + 255) / 256; ++j) {
        const int k = tid + j * 256;
        if (k < NPZD_NK) {
            const int w = k / NPZD_NSTEPS;          // magic-mul div
            const int s = k - w * NPZD_NSTEPS;
            const int g = lds_idx[w] + 3 * s;
            lds_f[w * NPZD_PAD + s] = frow[g];
            lds_m[w * NPZD_PAD + s] = mrow[g];
        }
    }
    __syncthreads();

    // Phase 2: lanes 0..51 integrate one trajectory each.
    if (tid >= NPZD_WK) return;
    const int w = tid;

    const float dt = dt_ptr[0];   // 0.125

    const float* xb = X_in + ((size_t)b * NPZD_WK + w) * 5;
    float N = xb[1], P = xb[2], Z = xb[3], D = xb[4];

    const float* pp = params + (size_t)b * 10;   // uniform -> SGPR loads
    const float chi   = pp[0];
    const float rho2  = pp[1] * 2.0f;
    const float gam1  = pp[2] * 0.1f;
    const float lam05 = pp[3] * 0.05f;
    const float eps1  = pp[4] * 0.1f;
    const float alp3  = pp[5] * 0.3f;
    const float bet6  = pp[6] * 0.6f;
    const float eta15 = pp[7] * 0.15f;
    const float phi4  = pp[8] * 0.4f;
    const float zet1  = pp[9] * 0.1f;
    const float rem   = 1.0f - alp3 - bet6;

    float oN[8], oP[8], oZ[8], oD[8];
    oN[0] = N; oP[0] = P; oZ[0] = Z; oD[0] = D;

    const float* lf = lds_f + w * NPZD_PAD;
    const float* lm = lds_m + w * NPZD_PAD;

    #pragma unroll
    for (int s = 0; s < NPZD_NSTEPS; ++s) {
        const float ft = lf[s], mt = lm[s];      // ds_read, const offset
        const float Pc = fmaxf(0.01f, P);
        const float Zc = fmaxf(0.01f, Z);
        const float gN = N / (chi + N);
        const float zg = rho2 * (1.0f - __expf(-lam05 * Pc)) * Zc;
        const float up = gN * ft * Pc;
        const float Nn = N + dt * (-up + alp3 * zg + eps1 * P + gam1 * Z + phi4 * D + mt * (8.0f - N));
        const float Pn = P + dt * (up - zg - eps1 * P - eta15 * P - mt * P);
        const float Zn = Z + dt * (bet6 * zg - gam1 * Z - mt * Z);
        const float Dn = D + dt * (eta15 * P + rem * zg - phi4 * D - zet1 * D - mt * D);
        N = Nn; P = Pn; Z = Zn; D = Dn;
        if ((s & 7) == 7) {
            const int c = (s >> 3) + 1;
            oN[c] = N; oP[c] = P; oZ[c] = Z; oD[c] = D;
        }
    }

    // Output: (b, w, state, 8) -> 32 contiguous floats per trajectory.
    // R1/R2 measured WRITE_SIZE == output bytes exactly -> no RMW penalty.
    float4* o4 = (float4*)(out + ((size_t)b * NPZD_WK + w) * 32);
    o4[0] = make_float4(oN[0], oN[1], oN[2], oN[3]);
    o4[1] = make_float4(oN[4], oN[5], oN[6], oN[7]);
    o4[2] = make_float4(oP[0], oP[1], oP[2], oP[3]);
    o4[3] = make_float4(oP[4], oP[5], oP[6], oP[7]);
    o4[4] = make_float4(oZ[0], oZ[1], oZ[2], oZ[3]);
    o4[5] = make_float4(oZ[4], oZ[5], oZ[6], oZ[7]);
    o4[6] = make_float4(oD[0], oD[1], oD[2], oD[3]);
    o4[7] = make_float4(oD[4], oD[5], oD[6], oD[7]);
}

extern "C" void kernel_launch(void* const* d_in, const int* in_sizes, int n_in,
                              void* d_out, int out_size, void* d_ws, size_t ws_size,
                              hipStream_t stream) {
    const float* X_in   = (const float*)d_in[0];
    const float* gf     = (const float*)d_in[1];
    const float* gm     = (const float*)d_in[2];
    const float* params = (const float*)d_in[3];
    const float* dt_ptr = (const float*)d_in[4];
    float* out = (float*)d_out;

    npzd_kernel<<<NPZD_B, 256, 0, stream>>>(X_in, gf, gm, params, dt_ptr, out);
}

// Round 4
// 180.707 us; speedup vs baseline: 1.0706x; 1.0083x over previous
//
#include <hip/hip_runtime.h>
#include <hip/hip_bf16.h>

// NPZD plankton ODE: B*WK = 106496 independent trajectories, 56 Euler steps.
// Memory-bound: ~143 MB unique forcing + 13.6 MB writes -> ~23 us HBM floor.
//
// R4: R3's cooperative LDS staging serialized (compiler emitted per-element
// load->vmcnt(0)->ds_write chains; VGPR=40 proved no loads in flight).
// Fix: LDS-DMA via __builtin_amdgcn_global_load_lds -- no VGPR round trip,
// all 24 gathers per wave issue back-to-back, single vmcnt drain at the
// barrier. DMA writes wave-uniform-base + lane*4, so the LDS layout must
// equal lane order: word(g,w,q) = g*208 + w*4 + q, s = 4g+q.
//   - DMA: 4 consecutive lanes = same week w, q=0..3 (12B stride, same line)
//   - compute: lane w reads 4 steps as one ds_read_b128 at 832g+16w
//     (standard stride-16 pattern, conflict-light; kills R3's 160k conflicts)

#define NPZD_B 2048
#define NPZD_WK 52
#define NPZD_HRS 8760
#define NPZD_NSTEPS 56
#define NPZD_NK 2912          // 52*56 = 14 s-groups * 208 words
#define NPZD_GRP 208          // words per s-group: 52 weeks * 4 samples
#define NPZD_LDSW 3072        // padded to 12*256 so the DMA loop has no tail

__global__ __launch_bounds__(256) void npzd_kernel(
    const float* __restrict__ X_in,     // (B, WK, 5, 1)
    const float* __restrict__ gf,       // (B, HRS)
    const float* __restrict__ gm,       // (B, HRS)
    const float* __restrict__ params,   // (B, 10)
    const float* __restrict__ dt_ptr,   // scalar
    float* __restrict__ out)            // (B, WK, 4, 8)
{
    __shared__ float lds_f[NPZD_LDSW];
    __shared__ float lds_m[NPZD_LDSW];

    const int b   = blockIdx.x;
    const int tid = threadIdx.x;

    const float* __restrict__ frow = gf + (size_t)b * NPZD_HRS;
    const float* __restrict__ mrow = gm + (size_t)b * NPZD_HRS;

    // ---- Phase 1: LDS-DMA all forcing for this batch ----
    // k in [0,3072): g=k/208, r=k%208, w=r/4, q=r&3; global = 168w+12g+3q.
    // k>=2912 loads harmless in-bounds garbage (max addr 6729 < 8760).
    // t0[w]=7w -> idx0=168w exact (verified fp32-exact R1-R3).
    #pragma unroll
    for (int j = 0; j < 12; ++j) {
        const unsigned k = (unsigned)(j * 256 + tid);
        const unsigned g = k / 208u;
        const unsigned r = k - g * 208u;
        const unsigned w = r >> 2;
        const unsigned q = r & 3u;
        const unsigned off = w * 168u + g * 12u + q * 3u;
        const int wb = j * 256 + (tid & 192);   // wave-uniform LDS word base
        __builtin_amdgcn_global_load_lds(
            (const __attribute__((address_space(1))) void*)(frow + off),
            (__attribute__((address_space(3))) void*)(lds_f + wb), 4, 0, 0);
        __builtin_amdgcn_global_load_lds(
            (const __attribute__((address_space(1))) void*)(mrow + off),
            (__attribute__((address_space(3))) void*)(lds_m + wb), 4, 0, 0);
    }
    __syncthreads();   // compiler emits the single vmcnt(0) drain here

    // ---- Phase 2: lanes 0..51 of wave 0 integrate one trajectory each ----
    if (tid >= NPZD_WK) return;
    const int w = tid;

    const float dt = dt_ptr[0];   // 0.125

    const float* xb = X_in + ((size_t)b * NPZD_WK + w) * 5;
    float N = xb[1], P = xb[2], Z = xb[3], D = xb[4];

    const float* pp = params + (size_t)b * 10;   // block-uniform -> s_load
    const float chi   = pp[0];
    const float rho2  = pp[1] * 2.0f;
    const float gam1  = pp[2] * 0.1f;
    const float lam05 = pp[3] * 0.05f;
    const float eps1  = pp[4] * 0.1f;
    const float alp3  = pp[5] * 0.3f;
    const float bet6  = pp[6] * 0.6f;
    const float eta15 = pp[7] * 0.15f;
    const float phi4  = pp[8] * 0.4f;
    const float zet1  = pp[9] * 0.1f;
    const float rem   = 1.0f - alp3 - bet6;

    float oN[8], oP[8], oZ[8], oD[8];
    oN[0] = N; oP[0] = P; oZ[0] = Z; oD[0] = D;

    #pragma unroll
    for (int g = 0; g < 14; ++g) {
        // one ds_read_b128 per array per 4 steps, stride 16B across lanes
        const float4 f4 = *(const float4*)(lds_f + g * NPZD_GRP + w * 4);
        const float4 m4 = *(const float4*)(lds_m + g * NPZD_GRP + w * 4);
        const float fs[4] = {f4.x, f4.y, f4.z, f4.w};
        const float ms[4] = {m4.x, m4.y, m4.z, m4.w};
        #pragma unroll
        for (int q = 0; q < 4; ++q) {
            const float ft = fs[q], mt = ms[q];
            const float Pc = fmaxf(0.01f, P);
            const float Zc = fmaxf(0.01f, Z);
            const float gN = N * __builtin_amdgcn_rcpf(chi + N);
            const float zg = rho2 * (1.0f - __expf(-lam05 * Pc)) * Zc;
            const float up = gN * ft * Pc;
            const float Nn = N + dt * (-up + alp3 * zg + eps1 * P + gam1 * Z + phi4 * D + mt * (8.0f - N));
            const float Pn = P + dt * (up - zg - eps1 * P - eta15 * P - mt * P);
            const float Zn = Z + dt * (bet6 * zg - gam1 * Z - mt * Z);
            const float Dn = D + dt * (eta15 * P + rem * zg - phi4 * D - zet1 * D - mt * D);
            N = Nn; P = Pn; Z = Zn; D = Dn;
        }
        if (g & 1) {   // after steps 7,15,...,55
            const int c = (g >> 1) + 1;
            oN[c] = N; oP[c] = P; oZ[c] = Z; oD[c] = D;
        }
    }

    // Output: (b, w, state, 8) -> 32 contiguous floats per trajectory.
    // R1-R3 measured WRITE_SIZE == output bytes exactly -> no RMW penalty.
    float4* o4 = (float4*)(out + ((size_t)b * NPZD_WK + w) * 32);
    o4[0] = make_float4(oN[0], oN[1], oN[2], oN[3]);
    o4[1] = make_float4(oN[4], oN[5], oN[6], oN[7]);
    o4[2] = make_float4(oP[0], oP[1], oP[2], oP[3]);
    o4[3] = make_float4(oP[4], oP[5], oP[6], oP[7]);
    o4[4] = make_float4(oZ[0], oZ[1], oZ[2], oZ[3]);
    o4[5] = make_float4(oZ[4], oZ[5], oZ[6], oZ[7]);
    o4[6] = make_float4(oD[0], oD[1], oD[2], oD[3]);
    o4[7] = make_float4(oD[4], oD[5], oD[6], oD[7]);
}

extern "C" void kernel_launch(void* const* d_in, const int* in_sizes, int n_in,
                              void* d_out, int out_size, void* d_ws, size_t ws_size,
                              hipStream_t stream) {
    const float* X_in   = (const float*)d_in[0];
    const float* gf     = (const float*)d_in[1];
    const float* gm     = (const float*)d_in[2];
    const float* params = (const float*)d_in[3];
    const float* dt_ptr = (const float*)d_in[4];
    float* out = (float*)d_out;

    npzd_kernel<<<NPZD_B, 256, 0, stream>>>(X_in, gf, gm, params, dt_ptr, out);
}

// Round 6
// 170.915 us; speedup vs baseline: 1.1320x; 1.0573x over previous
//
#include <hip/hip_runtime.h>
#include <hip/hip_bf16.h>

// NPZD plankton ODE: B*WK = 106496 independent trajectories, 56 Euler steps.
//
// R5/R6: R2-R4 all plateaued at 63-69 us regardless of load structure, and
// L3-warm dispatches (hbm_bytes ~= writes only) were JUST AS SLOW -> the
// invariant was the stride-3 gather's line-transaction count x latency /
// ~64 MSHRs per CU, not HBM bandwidth.
// Fix: the sampled hours are exactly h = 3j (168w+3s = 3(56w+s), bijective),
// so load the WHOLE gf/gm row per batch with perfectly-coalesced float4
// loads (each 64B line requested exactly once, zero address divergence),
// then compact every-3rd word into LDS. Trajectory w reads j in
// [56w,56w+56) -> LDS stride 60 (16B-aligned b128 reads, modest conflicts).
// (R6 = R5 with ext_vector float4: __builtin_nontemporal_load rejects
// HIP_vector_type.)

typedef float f32x4 __attribute__((ext_vector_type(4)));

#define NPZD_B 2048
#define NPZD_WK 52
#define NPZD_HRS 8760
#define NPZD_NSTEPS 56
#define NPZD_NF4 2190          // 8760/4 float4 per row
#define NPZD_WSTRIDE 60        // padded words per week (16B-aligned)
#define NPZD_LDSW (NPZD_WK * NPZD_WSTRIDE + 16)   // 3136; j up to 2919 -> p up to 3127

__global__ __launch_bounds__(256) void npzd_kernel(
    const float* __restrict__ X_in,     // (B, WK, 5, 1)
    const float* __restrict__ gf,       // (B, HRS)
    const float* __restrict__ gm,       // (B, HRS)
    const float* __restrict__ params,   // (B, 10)
    const float* __restrict__ dt_ptr,   // scalar
    float* __restrict__ out)            // (B, WK, 4, 8)
{
    __shared__ __align__(16) float lds_f[NPZD_LDSW];
    __shared__ __align__(16) float lds_m[NPZD_LDSW];

    const int b   = blockIdx.x;
    const int tid = threadIdx.x;

    const f32x4* __restrict__ gf4 = (const f32x4*)(gf + (size_t)b * NPZD_HRS);
    const f32x4* __restrict__ gm4 = (const f32x4*)(gm + (size_t)b * NPZD_HRS);

    // ---- Phase 1a: stage the whole row, fully coalesced, all in flight ----
    f32x4 fv[9], mv[9];
    int kk[9];
    #pragma unroll
    for (int i = 0; i < 9; ++i) {
        int k = i * 256 + tid;
        if (k >= NPZD_NF4) k = NPZD_NF4 - 1;   // clamp: dup load+dup write, benign
        kk[i] = k;
        fv[i] = __builtin_nontemporal_load(gf4 + k);
        mv[i] = __builtin_nontemporal_load(gm4 + k);
    }

    // ---- Phase 1b: compact every-3rd word into LDS ----
    // float4 k covers h = 4k..4k+3. h%3==0 at e0 = (3-k%3)%3 (and e0+3 if k%3==0).
    // j = h/3; dest p = j + 4*(j/56)  (= 60w + s). Magic div: j/56 = (j*9363)>>19
    // exact for j <= 2919.
    #pragma unroll
    for (int i = 0; i < 9; ++i) {
        const int k = kk[i];
        const float fe[4] = {fv[i].x, fv[i].y, fv[i].z, fv[i].w};
        const float me[4] = {mv[i].x, mv[i].y, mv[i].z, mv[i].w};
        const int rm = k % 3;
        const int e0 = (rm == 0) ? 0 : (3 - rm);
        const int j0 = (4 * k + e0) / 3;
        const int p0 = j0 + 4 * ((j0 * 9363) >> 19);
        lds_f[p0] = fe[e0];
        lds_m[p0] = me[e0];
        if (rm == 0) {               // second multiple of 3 in this float4 (e=3)
            const int j1 = j0 + 1;
            const int p1 = j1 + 4 * ((j1 * 9363) >> 19);
            lds_f[p1] = fe[3];
            lds_m[p1] = me[3];
        }
    }
    __syncthreads();

    // ---- Phase 2: lanes 0..51 of wave 0 integrate one trajectory each ----
    if (tid >= NPZD_WK) return;
    const int w = tid;

    const float dt = dt_ptr[0];   // 0.125

    const float* xb = X_in + ((size_t)b * NPZD_WK + w) * 5;
    float N = xb[1], P = xb[2], Z = xb[3], D = xb[4];

    const float* pp = params + (size_t)b * 10;   // block-uniform -> s_load
    const float chi   = pp[0];
    const float rho2  = pp[1] * 2.0f;
    const float gam1  = pp[2] * 0.1f;
    const float lam05 = pp[3] * 0.05f;
    const float eps1  = pp[4] * 0.1f;
    const float alp3  = pp[5] * 0.3f;
    const float bet6  = pp[6] * 0.6f;
    const float eta15 = pp[7] * 0.15f;
    const float phi4  = pp[8] * 0.4f;
    const float zet1  = pp[9] * 0.1f;
    const float rem   = 1.0f - alp3 - bet6;

    float oN[8], oP[8], oZ[8], oD[8];
    oN[0] = N; oP[0] = P; oZ[0] = Z; oD[0] = D;

    const float* lf = lds_f + w * NPZD_WSTRIDE;
    const float* lm = lds_m + w * NPZD_WSTRIDE;

    #pragma unroll
    for (int g = 0; g < 14; ++g) {
        // one aligned ds_read_b128 per array per 4 steps
        const f32x4 f4 = *(const f32x4*)(lf + 4 * g);
        const f32x4 m4 = *(const f32x4*)(lm + 4 * g);
        const float fs[4] = {f4.x, f4.y, f4.z, f4.w};
        const float ms[4] = {m4.x, m4.y, m4.z, m4.w};
        #pragma unroll
        for (int q = 0; q < 4; ++q) {
            const float ft = fs[q], mt = ms[q];
            const float Pc = fmaxf(0.01f, P);
            const float Zc = fmaxf(0.01f, Z);
            const float gN = N * __builtin_amdgcn_rcpf(chi + N);
            const float zg = rho2 * (1.0f - __expf(-lam05 * Pc)) * Zc;
            const float up = gN * ft * Pc;
            const float Nn = N + dt * (-up + alp3 * zg + eps1 * P + gam1 * Z + phi4 * D + mt * (8.0f - N));
            const float Pn = P + dt * (up - zg - eps1 * P - eta15 * P - mt * P);
            const float Zn = Z + dt * (bet6 * zg - gam1 * Z - mt * Z);
            const float Dn = D + dt * (eta15 * P + rem * zg - phi4 * D - zet1 * D - mt * D);
            N = Nn; P = Pn; Z = Zn; D = Dn;
        }
        if (g & 1) {   // after steps 7,15,...,55
            const int c = (g >> 1) + 1;
            oN[c] = N; oP[c] = P; oZ[c] = Z; oD[c] = D;
        }
    }

    // Output: (b, w, state, 8) -> 32 contiguous floats per trajectory.
    // R1-R4 measured WRITE_SIZE == output bytes exactly -> no RMW penalty.
    f32x4* o4 = (f32x4*)(out + ((size_t)b * NPZD_WK + w) * 32);
    o4[0] = (f32x4){oN[0], oN[1], oN[2], oN[3]};
    o4[1] = (f32x4){oN[4], oN[5], oN[6], oN[7]};
    o4[2] = (f32x4){oP[0], oP[1], oP[2], oP[3]};
    o4[3] = (f32x4){oP[4], oP[5], oP[6], oP[7]};
    o4[4] = (f32x4){oZ[0], oZ[1], oZ[2], oZ[3]};
    o4[5] = (f32x4){oZ[4], oZ[5], oZ[6], oZ[7]};
    o4[6] = (f32x4){oD[0], oD[1], oD[2], oD[3]};
    o4[7] = (f32x4){oD[4], oD[5], oD[6], oD[7]};
}

extern "C" void kernel_launch(void* const* d_in, const int* in_sizes, int n_in,
                              void* d_out, int out_size, void* d_ws, size_t ws_size,
                              hipStream_t stream) {
    const float* X_in   = (const float*)d_in[0];
    const float* gf     = (const float*)d_in[1];
    const float* gm     = (const float*)d_in[2];
    const float* params = (const float*)d_in[3];
    const float* dt_ptr = (const float*)d_in[4];
    float* out = (float*)d_out;

    npzd_kernel<<<NPZD_B, 256, 0, stream>>>(X_in, gf, gm, params, dt_ptr, out);
}